// Round 3
// baseline (3098.744 us; speedup 1.0000x reference)
//
#include <hip/hip_runtime.h>
#include <stdint.h>

// Problem constants (DeepseekMoE): N=8192 tokens, D=1024, H=2048, O=1024, E=8, K=2
#define N_TOK 8192
#define DIM   1024
#define HID   2048
#define OUTD  1024
#define NE    8
#define EPSBN 1e-5f

// GEMM tiling
#define TM 128
#define TN 128
#define BK 32
#define LSTR 40                // LDS row stride in u16 (32+8 pad -> 2-way bank alias, free)

#define RTILES 140             // worst case 136 routed tiles, padded
#define MPAD   (RTILES * 128)  // 17920 padded routed rows
#define STILES 64              // shared-expert M tiles (8192/128)

typedef unsigned short u16;
typedef __attribute__((ext_vector_type(8))) short short8;
typedef __attribute__((ext_vector_type(4))) float floatx4;

__device__ __forceinline__ float b2f(u16 h) {
    union { unsigned u; float f; } v; v.u = ((unsigned)h) << 16; return v.f;
}
__device__ __forceinline__ u16 f2b(float f) {
    union { float f; unsigned u; } v; v.f = f;
    unsigned r = v.u;
    r += 0x7fffu + ((r >> 16) & 1u);   // RNE
    return (u16)(r >> 16);
}
__device__ __forceinline__ short f2bs(float f) { return (short)f2b(f); }

// ---------------- dtype sniff: fp32 vs bf16 input arrays ----------------
// Low 16 bits of each 32-bit word: bf16 array -> a bf16 element (exponent
// bits 14..7 cluster near 127); fp32 array -> mantissa bits (uniform).
__global__ void k_dtype(const unsigned* __restrict__ x, int* __restrict__ flag) {
    __shared__ int cnt;
    if (threadIdx.x == 0) cnt = 0;
    __syncthreads();
    unsigned w = x[threadIdx.x];            // 256 words
    int e = (w >> 7) & 0xFF;
    if (e >= 100 && e <= 140) atomicAdd(&cnt, 1);
    __syncthreads();
    if (threadIdx.x == 0) flag[0] = (cnt < 128) ? 1 : 0;   // 1 = fp32
}

// ---------------- init ----------------
__global__ void k_init(int* token_list, int* counts) {
    int i = blockIdx.x * blockDim.x + threadIdx.x;
    if (i < MPAD) token_list[i] = -1;
    if (i < NE) counts[i] = 0;
}

// ---------------- gate ----------------
__global__ void k_gate(const void* __restrict__ xv, const void* __restrict__ wgv,
                       const int* __restrict__ flag,
                       int* __restrict__ topk_idx, float* __restrict__ topk_w,
                       int* __restrict__ counts) {
    const bool f32 = (*flag != 0);
    int wid  = (blockIdx.x * blockDim.x + threadIdx.x) >> 6;
    int lane = threadIdx.x & 63;
    if (wid >= N_TOK) return;
    float acc[NE];
#pragma unroll
    for (int e = 0; e < NE; e++) acc[e] = 0.f;
    for (int d = lane; d < DIM; d += 64) {
        float xvv = f32 ? ((const float*)xv)[(size_t)wid * DIM + d]
                        : b2f(((const u16*)xv)[(size_t)wid * DIM + d]);
#pragma unroll
        for (int e = 0; e < NE; e++) {
            float wv = f32 ? ((const float*)wgv)[e * DIM + d]
                           : b2f(((const u16*)wgv)[e * DIM + d]);
            acc[e] += xvv * wv;
        }
    }
#pragma unroll
    for (int e = 0; e < NE; e++)
        for (int off = 32; off; off >>= 1) acc[e] += __shfl_xor(acc[e], off, 64);
    if (lane == 0) {
        float mx = acc[0];
        for (int e = 1; e < NE; e++) mx = fmaxf(mx, acc[e]);
        float p[NE]; float s = 0.f;
        for (int e = 0; e < NE; e++) { p[e] = __expf(acc[e] - mx); s += p[e]; }
        float inv = 1.f / s;
        for (int e = 0; e < NE; e++) p[e] *= inv;
        int i0 = 0;
        for (int e = 1; e < NE; e++) if (p[e] > p[i0]) i0 = e;   // ties -> lower idx
        int i1 = (i0 == 0) ? 1 : 0;
        for (int e = 0; e < NE; e++) if (e != i0 && p[e] > p[i1]) i1 = e;
        float w0 = p[i0], w1 = p[i1];
        float wn = 1.f / (w0 + w1 + 1e-20f);
        topk_idx[wid * 2]     = i0; topk_idx[wid * 2 + 1] = i1;
        topk_w[wid * 2]       = w0 * wn; topk_w[wid * 2 + 1] = w1 * wn;
        atomicAdd(&counts[i0], 1); atomicAdd(&counts[i1], 1);
    }
}

// ---------------- plan: 128-aligned per-expert segments ----------------
__global__ void k_plan(const int* __restrict__ counts, int* __restrict__ cursor,
                       int* __restrict__ tile_expert) {
    if (threadIdx.x == 0) {
        int base = 0, t = 0;
        for (int e = 0; e < NE; e++) {
            cursor[e] = base;
            int nt = (counts[e] + 127) >> 7;
            for (int k = 0; k < nt; k++) tile_expert[t++] = e;
            base += nt * 128;
        }
        for (; t < 160; t++) tile_expert[t] = -1;
    }
}

// ---------------- scatter ----------------
__global__ void k_scatter(const int* __restrict__ topk_idx, const float* __restrict__ topk_w,
                          int* __restrict__ cursor, int* __restrict__ token_list,
                          float* __restrict__ row_weight) {
    int i = blockIdx.x * blockDim.x + threadIdx.x;
    if (i >= N_TOK * 2) return;
    int e = topk_idx[i];
    int pos = atomicAdd(&cursor[e], 1);
    token_list[pos] = i >> 1;
    row_weight[pos] = topk_w[i];
}

// ---------------- fused MFMA GEMM: C = epi(A @ B^T + bias) ----------------
// EPI 0: relu+BN -> bf16 C    EPI 1: sigmoid*w -> atomicAdd mout    EPI 2: sigmoid -> mout
// AEXT: A is an external input (dtype per flag); internal bufs are always bf16.
template <int EPI, bool GATHER, bool ROUTED, bool AEXT>
__global__ __launch_bounds__(256)
void k_gemm(const void* __restrict__ Av, const void* __restrict__ Bv,
            const int* __restrict__ flag, int aRowOff,
            int K, int Nout, size_t Bstride, size_t vecStride,
            const void* __restrict__ bias, const void* __restrict__ g,
            const void* __restrict__ be, const void* __restrict__ m,
            const void* __restrict__ v,
            const int* __restrict__ tile_expert, const int* __restrict__ token_list,
            const float* __restrict__ row_weight,
            u16* __restrict__ C, float* __restrict__ mout) {
    const bool f32 = (*flag != 0);
    const bool aF32 = AEXT && f32;
    int tileN = blockIdx.x, tileM = blockIdx.y;
    int expert = 0;
    if (ROUTED) {
        expert = tile_expert[tileM];
        if (expert < 0) return;
    }

    __shared__ u16 lA[TM * LSTR];
    __shared__ u16 lB[TN * LSTR];

    int tid = threadIdx.x;
    int lane = tid & 63;
    int wave = tid >> 6;
    int wm = wave & 1, wn = wave >> 1;

    int rl0 = wave * 32 + (lane >> 2);
    int rl1 = rl0 + 16;
    int colOff = (lane & 3) * 8;

    int gr0 = tileM * TM + rl0, gr1 = tileM * TM + rl1;
    if (GATHER) {
        int t0 = token_list[gr0]; if (t0 < 0) t0 = 0;
        int t1 = token_list[gr1]; if (t1 < 0) t1 = 0;
        gr0 = t0; gr1 = t1;
    }
    size_t arow0 = (size_t)(aRowOff + gr0), arow1 = (size_t)(aRowOff + gr1);
    size_t brow0 = (size_t)(tileN * TN + rl0), brow1 = (size_t)(tileN * TN + rl1);
    size_t bOff = (size_t)expert * Bstride;

    auto load8 = [&](const void* base, size_t eltOff, size_t row, int col, bool isf) -> short8 {
        if (isf) {
            const float* p = (const float*)base + eltOff + row * (size_t)K + col;
            const float4 u0 = *(const float4*)p;
            const float4 u1 = *(const float4*)(p + 4);
            short8 r;
            r[0] = f2bs(u0.x); r[1] = f2bs(u0.y); r[2] = f2bs(u0.z); r[3] = f2bs(u0.w);
            r[4] = f2bs(u1.x); r[5] = f2bs(u1.y); r[6] = f2bs(u1.z); r[7] = f2bs(u1.w);
            return r;
        }
        return *(const short8*)((const u16*)base + eltOff + row * (size_t)K + col);
    };

    floatx4 acc[4][4];
#pragma unroll
    for (int i = 0; i < 4; i++)
#pragma unroll
        for (int j = 0; j < 4; j++)
#pragma unroll
            for (int r = 0; r < 4; r++) acc[i][j][r] = 0.f;

    int lm = lane & 15, lq = lane >> 4;
    for (int k0 = 0; k0 < K; k0 += BK) {
        short8 a0 = load8(Av, 0, arow0, colOff + k0, aF32);
        short8 a1 = load8(Av, 0, arow1, colOff + k0, aF32);
        short8 b0 = load8(Bv, bOff, brow0, colOff + k0, f32);
        short8 b1 = load8(Bv, bOff, brow1, colOff + k0, f32);
        __syncthreads();   // previous iteration's LDS reads complete
        *(short8*)&lA[rl0 * LSTR + colOff] = a0;
        *(short8*)&lA[rl1 * LSTR + colOff] = a1;
        *(short8*)&lB[rl0 * LSTR + colOff] = b0;
        *(short8*)&lB[rl1 * LSTR + colOff] = b1;
        __syncthreads();
        short8 af[4], bfv[4];
#pragma unroll
        for (int i = 0; i < 4; i++)
            af[i] = *(const short8*)&lA[(wm * 64 + i * 16 + lm) * LSTR + lq * 8];
#pragma unroll
        for (int j = 0; j < 4; j++)
            bfv[j] = *(const short8*)&lB[(wn * 64 + j * 16 + lm) * LSTR + lq * 8];
#pragma unroll
        for (int i = 0; i < 4; i++)
#pragma unroll
            for (int j = 0; j < 4; j++)
                acc[i][j] = __builtin_amdgcn_mfma_f32_16x16x32_bf16(af[i], bfv[j], acc[i][j], 0, 0, 0);
    }

    auto ldv = [&](const void* p, size_t i) -> float {
        return f32 ? ((const float*)p)[i] : b2f(((const u16*)p)[i]);
    };

    // epilogue; C/D layout: col = lane&15, row = (lane>>4)*4 + reg  [m89-verified]
#pragma unroll
    for (int j = 0; j < 4; j++) {
        int colg = tileN * TN + wn * 64 + j * 16 + lm;
        float bb = ldv(bias, (size_t)expert * vecStride + colg);
        float sc = 0.f, sh = 0.f;
        if (EPI == 0) {
            sc = ldv(g, (size_t)expert * vecStride + colg) *
                 rsqrtf(ldv(v, (size_t)expert * vecStride + colg) + EPSBN);
            sh = ldv(be, (size_t)expert * vecStride + colg) -
                 ldv(m, (size_t)expert * vecStride + colg) * sc;
        }
#pragma unroll
        for (int i = 0; i < 4; i++) {
#pragma unroll
            for (int r = 0; r < 4; r++) {
                int rowg = tileM * TM + wm * 64 + i * 16 + lq * 4 + r;
                float val = acc[i][j][r] + bb;
                if (EPI == 0) {
                    val = fmaxf(val, 0.f) * sc + sh;
                    C[(size_t)rowg * Nout + colg] = f2b(val);
                } else if (EPI == 1) {
                    int tok = token_list[rowg];
                    if (tok >= 0) {
                        float sg = 1.f / (1.f + __expf(-val));
                        atomicAdd(&mout[(size_t)tok * Nout + colg], sg * row_weight[rowg]);
                    }
                } else {
                    mout[(size_t)rowg * Nout + colg] = 1.f / (1.f + __expf(-val));
                }
            }
        }
    }
}

// ---------------- finalize ----------------
__global__ void k_final(const float* __restrict__ mout, void* __restrict__ out,
                        const int* __restrict__ flag) {
    int i = blockIdx.x * blockDim.x + threadIdx.x;
    if (i >= N_TOK * OUTD) return;
    if (*flag) ((float*)out)[i] = mout[i];
    else       ((u16*)out)[i]   = f2b(mout[i]);
}

extern "C" void kernel_launch(void* const* d_in, const int* in_sizes, int n_in,
                              void* d_out, int out_size, void* d_ws, size_t ws_size,
                              hipStream_t stream) {
    const void* x   = d_in[0];
    const void* Wg  = d_in[1];
    const void* W1  = d_in[2];
    const void* b1  = d_in[3];
    const void* g1  = d_in[4];
    const void* be1 = d_in[5];
    const void* m1  = d_in[6];
    const void* v1  = d_in[7];
    const void* W2  = d_in[8];
    const void* b2  = d_in[9];
    const void* g2  = d_in[10];
    const void* be2 = d_in[11];
    const void* m2  = d_in[12];
    const void* v2  = d_in[13];
    const void* W3  = d_in[14];
    const void* b3  = d_in[15];
    const void* sW1 = d_in[16];
    const void* sb1 = d_in[17];
    const void* sg1 = d_in[18];
    const void* sbe1= d_in[19];
    const void* sm1 = d_in[20];
    const void* sv1 = d_in[21];
    const void* sW2 = d_in[22];
    const void* sb2 = d_in[23];
    const void* sg2 = d_in[24];
    const void* sbe2= d_in[25];
    const void* sm2 = d_in[26];
    const void* sv2 = d_in[27];
    const void* sW3 = d_in[28];
    const void* sb3 = d_in[29];

    // ---- workspace layout ----
    char* ws = (char*)d_ws;
    int*   counts      = (int*)(ws + 0);
    int*   cursor      = (int*)(ws + 64);
    int*   flag        = (int*)(ws + 512);
    int*   tile_expert = (int*)(ws + 1024);           // 160 ints
    int*   topk_idx    = (int*)(ws + 4096);           // 64 KB
    float* topk_w      = (float*)(ws + 131072);       // 64 KB
    int*   token_list  = (int*)(ws + 262144);         // 70 KB
    float* row_weight  = (float*)(ws + 393216);       // 70 KB
    float* mout        = (float*)(ws + 1048576);      // 32 MB fp32 [N,O]
    const size_t bufStart = 34603008;                 // after mout
    // tiles per chunk, adaptive to ws_size (1 MB per tile across both bufs)
    size_t avail = (ws_size > bufStart) ? (ws_size - bufStart) : 0;
    int cm = (int)(avail / (2ull * 128 * HID * 2));
    if (cm > 28) cm = 28;
    if (cm < 1)  cm = 1;
    u16* bufA = (u16*)(ws + bufStart);
    u16* bufB = (u16*)(ws + bufStart + (size_t)cm * 128 * HID * 2);

    dim3 blk(256);

    k_dtype<<<1, 256, 0, stream>>>((const unsigned*)x, flag);
    k_init<<<(MPAD + 255) / 256, blk, 0, stream>>>(token_list, counts);
    k_gate<<<N_TOK / 4, blk, 0, stream>>>(x, Wg, flag, topk_idx, topk_w, counts);
    k_plan<<<1, 64, 0, stream>>>(counts, cursor, tile_expert);
    k_scatter<<<(N_TOK * 2 + 255) / 256, blk, 0, stream>>>(topk_idx, topk_w, cursor,
                                                           token_list, row_weight);

    // shared expert: x -> s1(bufA) -> s2(bufB) -> mout (fp32 '=' store inits mout)
    for (int off = 0; off < STILES; off += cm) {
        int nt = (STILES - off < cm) ? (STILES - off) : cm;
        k_gemm<0, false, false, true><<<dim3(HID / TN, nt), blk, 0, stream>>>(
            x, sW1, flag, off * 128, DIM, HID, 0, 0,
            sb1, sg1, sbe1, sm1, sv1, nullptr, nullptr, nullptr, bufA, nullptr);
        k_gemm<0, false, false, false><<<dim3(HID / TN, nt), blk, 0, stream>>>(
            bufA, sW2, flag, 0, HID, HID, 0, 0,
            sb2, sg2, sbe2, sm2, sv2, nullptr, nullptr, nullptr, bufB, nullptr);
        k_gemm<2, false, false, false><<<dim3(OUTD / TN, nt), blk, 0, stream>>>(
            bufB, sW3, flag, 0, HID, OUTD, 0, 0,
            sb3, nullptr, nullptr, nullptr, nullptr,
            nullptr, nullptr, nullptr, nullptr, mout + (size_t)off * 128 * OUTD);
    }

    // routed experts: x(gather) -> h1(bufA) -> h2(bufB) -> atomicAdd mout
    for (int ro = 0; ro < RTILES; ro += cm) {
        int nt = (RTILES - ro < cm) ? (RTILES - ro) : cm;
        k_gemm<0, true, true, true><<<dim3(HID / TN, nt), blk, 0, stream>>>(
            x, W1, flag, 0, DIM, HID, (size_t)HID * DIM, HID,
            b1, g1, be1, m1, v1,
            tile_expert + ro, token_list + (size_t)ro * 128, nullptr, bufA, nullptr);
        k_gemm<0, false, true, false><<<dim3(HID / TN, nt), blk, 0, stream>>>(
            bufA, W2, flag, 0, HID, HID, (size_t)HID * HID, HID,
            b2, g2, be2, m2, v2,
            tile_expert + ro, nullptr, nullptr, bufB, nullptr);
        k_gemm<1, false, true, false><<<dim3(OUTD / TN, nt), blk, 0, stream>>>(
            bufB, W3, flag, 0, HID, OUTD, (size_t)OUTD * HID, OUTD,
            b3, nullptr, nullptr, nullptr, nullptr,
            tile_expert + ro, token_list + (size_t)ro * 128, row_weight + (size_t)ro * 128,
            nullptr, mout);
    }

    k_final<<<(N_TOK * OUTD + 255) / 256, blk, 0, stream>>>(mout, d_out, flag);
}

// Round 4
// 1290.018 us; speedup vs baseline: 2.4021x; 2.4021x over previous
//
#include <hip/hip_runtime.h>
#include <stdint.h>

// DeepseekMoE: N=8192 tokens, D=1024, H=2048, O=1024, E=8, K=2. All inputs fp32, output fp32.
#define N_TOK 8192
#define DIM   1024
#define HID   2048
#define OUTD  1024
#define NE    8
#define EPSBN 1e-5f

#define TM 128
#define TN 128
#define BK 32
#define LSTR 40                // tier-B LDS row stride (padded)

#define RTILES 140             // worst case 136 routed tiles, padded
#define MPAD   (RTILES * 128)
#define STILES 64              // shared-expert M tiles

typedef unsigned short u16;
typedef __attribute__((ext_vector_type(8))) short short8;
typedef __attribute__((ext_vector_type(4))) float floatx4;

__device__ __forceinline__ float b2f(u16 h) {
    union { unsigned u; float f; } v; v.u = ((unsigned)h) << 16; return v.f;
}
__device__ __forceinline__ u16 f2b(float f) {
    union { float f; unsigned u; } v; v.f = f;
    unsigned r = v.u;
    r += 0x7fffu + ((r >> 16) & 1u);   // RNE
    return (u16)(r >> 16);
}
__device__ __forceinline__ short f2bs(float f) { return (short)f2b(f); }

typedef __attribute__((address_space(1))) const unsigned char ga_t;
typedef __attribute__((address_space(3))) unsigned char lds_t;
__device__ __forceinline__ void gload16(const void* g, void* l) {
    __builtin_amdgcn_global_load_lds((ga_t*)g, (lds_t*)l, 16, 0, 0);
}

// ---------------- fp32 -> bf16 convert (vectorized) ----------------
__global__ void k_cvt(const float* __restrict__ s, u16* __restrict__ d, int n4) {
    int i = blockIdx.x * blockDim.x + threadIdx.x;
    if (i >= n4) return;
    float4 v = ((const float4*)s)[i];
    u16 o0 = f2b(v.x), o1 = f2b(v.y), o2 = f2b(v.z), o3 = f2b(v.w);
    ulong1 pack;   // 8B store
    unsigned long long w = (unsigned long long)o0 | ((unsigned long long)o1 << 16)
                         | ((unsigned long long)o2 << 32) | ((unsigned long long)o3 << 48);
    pack.x = w;
    ((ulong1*)d)[i] = pack;
}

// ---------------- init ----------------
__global__ void k_init(int* token_list, int* counts) {
    int i = blockIdx.x * blockDim.x + threadIdx.x;
    if (i < MPAD) token_list[i] = -1;
    if (i < NE) counts[i] = 0;
}

// ---------------- gate: fp32 scores, softmax, top-2, renorm (no atomics) ----------------
__global__ void k_gate(const float* __restrict__ x, const float* __restrict__ wg,
                       int* __restrict__ topk_idx, float* __restrict__ topk_w) {
    int wid  = (blockIdx.x * blockDim.x + threadIdx.x) >> 6; // one wave per token
    int lane = threadIdx.x & 63;
    if (wid >= N_TOK) return;
    const float4* xr = (const float4*)(x + (size_t)wid * DIM);
    float acc[NE];
#pragma unroll
    for (int e = 0; e < NE; e++) acc[e] = 0.f;
#pragma unroll
    for (int it = 0; it < DIM / 4 / 64; it++) {
        int d = lane + it * 64;
        float4 xv = xr[d];
#pragma unroll
        for (int e = 0; e < NE; e++) {
            float4 wv = ((const float4*)(wg + (size_t)e * DIM))[d];
            acc[e] += xv.x * wv.x + xv.y * wv.y + xv.z * wv.z + xv.w * wv.w;
        }
    }
#pragma unroll
    for (int e = 0; e < NE; e++)
        for (int off = 32; off; off >>= 1) acc[e] += __shfl_xor(acc[e], off, 64);
    if (lane == 0) {
        float mx = acc[0];
        for (int e = 1; e < NE; e++) mx = fmaxf(mx, acc[e]);
        float p[NE]; float s = 0.f;
        for (int e = 0; e < NE; e++) { p[e] = __expf(acc[e] - mx); s += p[e]; }
        float inv = 1.f / s;
        for (int e = 0; e < NE; e++) p[e] *= inv;
        int i0 = 0;
        for (int e = 1; e < NE; e++) if (p[e] > p[i0]) i0 = e;   // ties -> lower idx (jax)
        int i1 = (i0 == 0) ? 1 : 0;
        for (int e = 0; e < NE; e++) if (e != i0 && p[e] > p[i1]) i1 = e;
        float w0 = p[i0], w1 = p[i1];
        float wn = 1.f / (w0 + w1 + 1e-20f);
        topk_idx[wid * 2]     = i0; topk_idx[wid * 2 + 1] = i1;
        topk_w[wid * 2]       = w0 * wn; topk_w[wid * 2 + 1] = w1 * wn;
    }
}

// ---------------- count: LDS histogram -> 8 global atomics per block ----------------
__global__ void k_count(const int* __restrict__ topk_idx, int* __restrict__ counts) {
    __shared__ int h[NE];
    int tid = threadIdx.x;
    if (tid < NE) h[tid] = 0;
    __syncthreads();
    int i = blockIdx.x * blockDim.x + tid;
    if (i < N_TOK * 2) atomicAdd(&h[topk_idx[i]], 1);
    __syncthreads();
    if (tid < NE) atomicAdd(&counts[tid], h[tid]);
}

// ---------------- plan: 128-aligned per-expert segments ----------------
__global__ void k_plan(const int* __restrict__ counts, int* __restrict__ cursor,
                       int* __restrict__ tile_expert) {
    if (threadIdx.x == 0) {
        int base = 0, t = 0;
        for (int e = 0; e < NE; e++) {
            cursor[e] = base;
            int nt = (counts[e] + 127) >> 7;
            for (int k = 0; k < nt; k++) tile_expert[t++] = e;
            base += nt * 128;
        }
        for (; t < 160; t++) tile_expert[t] = -1;
    }
}

// ---------------- scatter: two-level (LDS hist -> 1 atomic/expert/block -> LDS rank) ----------------
__global__ void k_scatter(const int* __restrict__ topk_idx, const float* __restrict__ topk_w,
                          int* __restrict__ cursor, int* __restrict__ token_list,
                          float* __restrict__ row_weight) {
    __shared__ int h[NE], base[NE], rk[NE];
    int tid = threadIdx.x;
    if (tid < NE) { h[tid] = 0; rk[tid] = 0; }
    __syncthreads();
    int i = blockIdx.x * blockDim.x + tid;
    int e = (i < N_TOK * 2) ? topk_idx[i] : -1;
    if (e >= 0) atomicAdd(&h[e], 1);
    __syncthreads();
    if (tid < NE) base[tid] = atomicAdd(&cursor[tid], h[tid]);
    __syncthreads();
    if (e >= 0) {
        int pos = base[e] + atomicAdd(&rk[e], 1);
        token_list[pos] = i >> 1;
        row_weight[pos] = topk_w[i];
    }
}

// ================= tier A GEMM: all-bf16, global_load_lds staging (m97 recipe) =================
// EPI 0: relu+BN -> bf16 C    EPI 1: sigmoid*w -> atomicAdd out(f32)    EPI 2: sigmoid -> out(f32)
template <int EPI, bool GATHER, bool ROUTED>
__global__ __launch_bounds__(256)
void k_gemm_a(const u16* __restrict__ A, const u16* __restrict__ Bw,
              int K, int Nout, size_t Bstride, size_t vecStride,
              const float* __restrict__ bias, const float* __restrict__ g,
              const float* __restrict__ be, const float* __restrict__ m,
              const float* __restrict__ v,
              const int* __restrict__ tile_expert, const int* __restrict__ token_list,
              const float* __restrict__ row_weight,
              u16* __restrict__ C, float* __restrict__ outp) {
    int tileN = blockIdx.x, tileM = blockIdx.y;
    int expert = 0;
    if (ROUTED) {
        expert = tile_expert[tileM];
        if (expert < 0) return;
    }
    const u16* Bp = Bw + (size_t)expert * Bstride;

    __shared__ u16 lA[TM * BK];
    __shared__ u16 lB[TN * BK];

    int tid = threadIdx.x;
    int lane = tid & 63;
    int wave = tid >> 6;
    int wm = wave & 1, wn = wave >> 1;

    int rl0 = wave * 32 + (lane >> 2);
    int rl1 = rl0 + 16;
    int colOff = (lane & 3) * 8;

    int gr0 = tileM * TM + rl0, gr1 = tileM * TM + rl1;
    if (GATHER) {
        int t0 = token_list[gr0]; if (t0 < 0) t0 = 0;
        int t1 = token_list[gr1]; if (t1 < 0) t1 = 0;
        gr0 = t0; gr1 = t1;
    }
    const u16* aP0 = A + (size_t)gr0 * K + colOff;
    const u16* aP1 = A + (size_t)gr1 * K + colOff;
    const u16* bP0 = Bp + (size_t)(tileN * TN + rl0) * K + colOff;
    const u16* bP1 = Bp + (size_t)(tileN * TN + rl1) * K + colOff;
    u16* lA0 = lA + (size_t)(wave * 32) * BK;
    u16* lA1 = lA + (size_t)(wave * 32 + 16) * BK;
    u16* lB0 = lB + (size_t)(wave * 32) * BK;
    u16* lB1 = lB + (size_t)(wave * 32 + 16) * BK;

    floatx4 acc[4][4];
#pragma unroll
    for (int i = 0; i < 4; i++)
#pragma unroll
        for (int j = 0; j < 4; j++)
#pragma unroll
            for (int r = 0; r < 4; r++) acc[i][j][r] = 0.f;

    int lm = lane & 15, lq = lane >> 4;
    for (int k0 = 0; k0 < K; k0 += BK) {
        gload16(aP0 + k0, lA0);
        gload16(aP1 + k0, lA1);
        gload16(bP0 + k0, lB0);
        gload16(bP1 + k0, lB1);
        asm volatile("s_waitcnt vmcnt(0)" ::: "memory");
        __syncthreads();
        short8 af[4], bfv[4];
#pragma unroll
        for (int i = 0; i < 4; i++)
            af[i] = *(const short8*)&lA[(wm * 64 + i * 16 + lm) * BK + lq * 8];
#pragma unroll
        for (int j = 0; j < 4; j++)
            bfv[j] = *(const short8*)&lB[(wn * 64 + j * 16 + lm) * BK + lq * 8];
#pragma unroll
        for (int i = 0; i < 4; i++)
#pragma unroll
            for (int j = 0; j < 4; j++)
                acc[i][j] = __builtin_amdgcn_mfma_f32_16x16x32_bf16(af[i], bfv[j], acc[i][j], 0, 0, 0);
        __syncthreads();
    }

    // epilogue; C/D layout: col = lane&15, row = (lane>>4)*4 + reg  [m89-verified]
#pragma unroll
    for (int j = 0; j < 4; j++) {
        int colg = tileN * TN + wn * 64 + j * 16 + lm;
        float bb = bias[(size_t)expert * vecStride + colg];
        float sc = 0.f, sh = 0.f;
        if (EPI == 0) {
            sc = g[(size_t)expert * vecStride + colg] *
                 rsqrtf(v[(size_t)expert * vecStride + colg] + EPSBN);
            sh = be[(size_t)expert * vecStride + colg] -
                 m[(size_t)expert * vecStride + colg] * sc;
        }
#pragma unroll
        for (int i = 0; i < 4; i++) {
#pragma unroll
            for (int r = 0; r < 4; r++) {
                int rowg = tileM * TM + wm * 64 + i * 16 + lq * 4 + r;
                float val = acc[i][j][r] + bb;
                if (EPI == 0) {
                    val = fmaxf(val, 0.f) * sc + sh;
                    C[(size_t)rowg * Nout + colg] = f2b(val);
                } else if (EPI == 1) {
                    int tok = token_list[rowg];
                    if (tok >= 0) {
                        float sg = 1.f / (1.f + __expf(-val));
                        atomicAdd(&outp[(size_t)tok * Nout + colg], sg * row_weight[rowg]);
                    }
                } else {
                    outp[(size_t)rowg * Nout + colg] = 1.f / (1.f + __expf(-val));
                }
            }
        }
    }
}

// ================= tier B GEMM: fp32 on-the-fly convert staging (proven R3) =================
template <int EPI, bool GATHER, bool ROUTED, bool AF32>
__global__ __launch_bounds__(256)
void k_gemm_b(const void* __restrict__ Av, const float* __restrict__ Bw,
              int K, int Nout, size_t Bstride, size_t vecStride,
              const float* __restrict__ bias, const float* __restrict__ g,
              const float* __restrict__ be, const float* __restrict__ m,
              const float* __restrict__ v,
              const int* __restrict__ tile_expert, const int* __restrict__ token_list,
              const float* __restrict__ row_weight,
              u16* __restrict__ C, float* __restrict__ outp) {
    int tileN = blockIdx.x, tileM = blockIdx.y;
    int expert = 0;
    if (ROUTED) {
        expert = tile_expert[tileM];
        if (expert < 0) return;
    }

    __shared__ u16 lA[TM * LSTR];
    __shared__ u16 lB[TN * LSTR];

    int tid = threadIdx.x;
    int lane = tid & 63;
    int wave = tid >> 6;
    int wm = wave & 1, wn = wave >> 1;

    int rl0 = wave * 32 + (lane >> 2);
    int rl1 = rl0 + 16;
    int colOff = (lane & 3) * 8;

    int gr0 = tileM * TM + rl0, gr1 = tileM * TM + rl1;
    if (GATHER) {
        int t0 = token_list[gr0]; if (t0 < 0) t0 = 0;
        int t1 = token_list[gr1]; if (t1 < 0) t1 = 0;
        gr0 = t0; gr1 = t1;
    }
    size_t bOff = (size_t)expert * Bstride;

    auto load8f = [&](const float* p) -> short8 {
        const float4 u0 = *(const float4*)p;
        const float4 u1 = *(const float4*)(p + 4);
        short8 r;
        r[0] = f2bs(u0.x); r[1] = f2bs(u0.y); r[2] = f2bs(u0.z); r[3] = f2bs(u0.w);
        r[4] = f2bs(u1.x); r[5] = f2bs(u1.y); r[6] = f2bs(u1.z); r[7] = f2bs(u1.w);
        return r;
    };

    floatx4 acc[4][4];
#pragma unroll
    for (int i = 0; i < 4; i++)
#pragma unroll
        for (int j = 0; j < 4; j++)
#pragma unroll
            for (int r = 0; r < 4; r++) acc[i][j][r] = 0.f;

    int lm = lane & 15, lq = lane >> 4;
    for (int k0 = 0; k0 < K; k0 += BK) {
        short8 a0, a1;
        if (AF32) {
            a0 = load8f((const float*)Av + (size_t)gr0 * K + colOff + k0);
            a1 = load8f((const float*)Av + (size_t)gr1 * K + colOff + k0);
        } else {
            a0 = *(const short8*)((const u16*)Av + (size_t)gr0 * K + colOff + k0);
            a1 = *(const short8*)((const u16*)Av + (size_t)gr1 * K + colOff + k0);
        }
        short8 b0 = load8f(Bw + bOff + (size_t)(tileN * TN + rl0) * K + colOff + k0);
        short8 b1 = load8f(Bw + bOff + (size_t)(tileN * TN + rl1) * K + colOff + k0);
        __syncthreads();
        *(short8*)&lA[rl0 * LSTR + colOff] = a0;
        *(short8*)&lA[rl1 * LSTR + colOff] = a1;
        *(short8*)&lB[rl0 * LSTR + colOff] = b0;
        *(short8*)&lB[rl1 * LSTR + colOff] = b1;
        __syncthreads();
        short8 af[4], bfv[4];
#pragma unroll
        for (int i = 0; i < 4; i++)
            af[i] = *(const short8*)&lA[(wm * 64 + i * 16 + lm) * LSTR + lq * 8];
#pragma unroll
        for (int j = 0; j < 4; j++)
            bfv[j] = *(const short8*)&lB[(wn * 64 + j * 16 + lm) * LSTR + lq * 8];
#pragma unroll
        for (int i = 0; i < 4; i++)
#pragma unroll
            for (int j = 0; j < 4; j++)
                acc[i][j] = __builtin_amdgcn_mfma_f32_16x16x32_bf16(af[i], bfv[j], acc[i][j], 0, 0, 0);
    }

#pragma unroll
    for (int j = 0; j < 4; j++) {
        int colg = tileN * TN + wn * 64 + j * 16 + lm;
        float bb = bias[(size_t)expert * vecStride + colg];
        float sc = 0.f, sh = 0.f;
        if (EPI == 0) {
            sc = g[(size_t)expert * vecStride + colg] *
                 rsqrtf(v[(size_t)expert * vecStride + colg] + EPSBN);
            sh = be[(size_t)expert * vecStride + colg] -
                 m[(size_t)expert * vecStride + colg] * sc;
        }
#pragma unroll
        for (int i = 0; i < 4; i++) {
#pragma unroll
            for (int r = 0; r < 4; r++) {
                int rowg = tileM * TM + wm * 64 + i * 16 + lq * 4 + r;
                float val = acc[i][j][r] + bb;
                if (EPI == 0) {
                    val = fmaxf(val, 0.f) * sc + sh;
                    C[(size_t)rowg * Nout + colg] = f2b(val);
                } else if (EPI == 1) {
                    int tok = token_list[rowg];
                    if (tok >= 0) {
                        float sg = 1.f / (1.f + __expf(-val));
                        atomicAdd(&outp[(size_t)tok * Nout + colg], sg * row_weight[rowg]);
                    }
                } else {
                    outp[(size_t)rowg * Nout + colg] = 1.f / (1.f + __expf(-val));
                }
            }
        }
    }
}

extern "C" void kernel_launch(void* const* d_in, const int* in_sizes, int n_in,
                              void* d_out, int out_size, void* d_ws, size_t ws_size,
                              hipStream_t stream) {
    const float* x   = (const float*)d_in[0];
    const float* Wg  = (const float*)d_in[1];
    const float* W1  = (const float*)d_in[2];
    const float* b1  = (const float*)d_in[3];
    const float* g1  = (const float*)d_in[4];
    const float* be1 = (const float*)d_in[5];
    const float* m1  = (const float*)d_in[6];
    const float* v1  = (const float*)d_in[7];
    const float* W2  = (const float*)d_in[8];
    const float* b2  = (const float*)d_in[9];
    const float* g2  = (const float*)d_in[10];
    const float* be2 = (const float*)d_in[11];
    const float* m2  = (const float*)d_in[12];
    const float* v2  = (const float*)d_in[13];
    const float* W3  = (const float*)d_in[14];
    const float* b3  = (const float*)d_in[15];
    const float* sW1 = (const float*)d_in[16];
    const float* sb1 = (const float*)d_in[17];
    const float* sg1 = (const float*)d_in[18];
    const float* sbe1= (const float*)d_in[19];
    const float* sm1 = (const float*)d_in[20];
    const float* sv1 = (const float*)d_in[21];
    const float* sW2 = (const float*)d_in[22];
    const float* sb2 = (const float*)d_in[23];
    const float* sg2 = (const float*)d_in[24];
    const float* sbe2= (const float*)d_in[25];
    const float* sm2 = (const float*)d_in[26];
    const float* sv2 = (const float*)d_in[27];
    const float* sW3 = (const float*)d_in[28];
    const float* sb3 = (const float*)d_in[29];
    float* out = (float*)d_out;

    char* ws = (char*)d_ws;
    int*   counts      = (int*)(ws + 0);
    int*   cursor      = (int*)(ws + 64);
    int*   tile_expert = (int*)(ws + 1024);
    int*   topk_idx    = (int*)(ws + 4096);
    float* topk_w      = (float*)(ws + 131072);
    int*   token_list  = (int*)(ws + 262144);
    float* row_weight  = (float*)(ws + 393216);
    const size_t metaEnd = 1ull << 20;

    dim3 blk(256);

    // routing metadata
    k_init<<<(MPAD + 255) / 256, blk, 0, stream>>>(token_list, counts);
    k_gate<<<N_TOK / 4, blk, 0, stream>>>(x, Wg, topk_idx, topk_w);
    k_count<<<(N_TOK * 2) / 256, blk, 0, stream>>>(topk_idx, counts);
    k_plan<<<1, 64, 0, stream>>>(counts, cursor, tile_expert);
    k_scatter<<<(N_TOK * 2) / 256, blk, 0, stream>>>(topk_idx, topk_w, cursor,
                                                     token_list, row_weight);

    // tier A layout: bf16 copies of x + all weights, then chunk buffers
    size_t o_xb = metaEnd,        s_xb = (size_t)N_TOK * DIM * 2;
    size_t o_W1 = o_xb + s_xb,    s_W1 = (size_t)NE * HID * DIM * 2;
    size_t o_W2 = o_W1 + s_W1,    s_W2 = (size_t)NE * HID * HID * 2;
    size_t o_W3 = o_W2 + s_W2,    s_W3 = (size_t)NE * OUTD * HID * 2;
    size_t o_s1 = o_W3 + s_W3,    s_s1 = (size_t)HID * DIM * 2;
    size_t o_s2 = o_s1 + s_s1,    s_s2 = (size_t)HID * HID * 2;
    size_t o_s3 = o_s2 + s_s2,    s_s3 = (size_t)OUTD * HID * 2;
    size_t o_buf = o_s3 + s_s3;                      // ~169 MB
    const size_t tileBytes = (size_t)128 * HID * 2;  // 512 KB per buf per tile
    bool tierA = ws_size >= o_buf + 16ull * tileBytes * 2;

    if (tierA) {
        int cm = (int)((ws_size - o_buf) / (2 * tileBytes));
        if (cm > RTILES) cm = RTILES;
        u16* xb  = (u16*)(ws + o_xb);
        u16* W1b = (u16*)(ws + o_W1);
        u16* W2b = (u16*)(ws + o_W2);
        u16* W3b = (u16*)(ws + o_W3);
        u16* s1b = (u16*)(ws + o_s1);
        u16* s2b = (u16*)(ws + o_s2);
        u16* s3b = (u16*)(ws + o_s3);
        u16* bufA = (u16*)(ws + o_buf);
        u16* bufB = (u16*)(ws + o_buf + (size_t)cm * tileBytes);

        auto cvt = [&](const float* s, u16* d, size_t n) {
            int n4 = (int)(n / 4);
            k_cvt<<<(n4 + 255) / 256, blk, 0, stream>>>(s, d, n4);
        };
        cvt(x,   xb,  (size_t)N_TOK * DIM);
        cvt(W1,  W1b, (size_t)NE * HID * DIM);
        cvt(W2,  W2b, (size_t)NE * HID * HID);
        cvt(W3,  W3b, (size_t)NE * OUTD * HID);
        cvt(sW1, s1b, (size_t)HID * DIM);
        cvt(sW2, s2b, (size_t)HID * HID);
        cvt(sW3, s3b, (size_t)OUTD * HID);

        // shared expert (writes out with '=', initializing it)
        for (int off = 0; off < STILES; off += cm) {
            int nt = (STILES - off < cm) ? (STILES - off) : cm;
            k_gemm_a<0, false, false><<<dim3(HID / TN, nt), blk, 0, stream>>>(
                xb + (size_t)off * 128 * DIM, s1b, DIM, HID, 0, 0,
                sb1, sg1, sbe1, sm1, sv1, nullptr, nullptr, nullptr, bufA, nullptr);
            k_gemm_a<0, false, false><<<dim3(HID / TN, nt), blk, 0, stream>>>(
                bufA, s2b, HID, HID, 0, 0,
                sb2, sg2, sbe2, sm2, sv2, nullptr, nullptr, nullptr, bufB, nullptr);
            k_gemm_a<2, false, false><<<dim3(OUTD / TN, nt), blk, 0, stream>>>(
                bufB, s3b, HID, OUTD, 0, 0,
                sb3, nullptr, nullptr, nullptr, nullptr,
                nullptr, nullptr, nullptr, nullptr, out + (size_t)off * 128 * OUTD);
        }
        // routed experts (atomicAdd into out)
        for (int ro = 0; ro < RTILES; ro += cm) {
            int nt = (RTILES - ro < cm) ? (RTILES - ro) : cm;
            k_gemm_a<0, true, true><<<dim3(HID / TN, nt), blk, 0, stream>>>(
                xb, W1b, DIM, HID, (size_t)HID * DIM, HID,
                b1, g1, be1, m1, v1,
                tile_expert + ro, token_list + (size_t)ro * 128, nullptr, bufA, nullptr);
            k_gemm_a<0, false, true><<<dim3(HID / TN, nt), blk, 0, stream>>>(
                bufA, W2b, HID, HID, (size_t)HID * HID, HID,
                b2, g2, be2, m2, v2,
                tile_expert + ro, nullptr, nullptr, bufB, nullptr);
            k_gemm_a<1, false, true><<<dim3(OUTD / TN, nt), blk, 0, stream>>>(
                bufB, W3b, HID, OUTD, (size_t)OUTD * HID, OUTD,
                b3, nullptr, nullptr, nullptr, nullptr,
                tile_expert + ro, token_list + (size_t)ro * 128, row_weight + (size_t)ro * 128,
                nullptr, out);
        }
    } else {
        // tier B: on-the-fly conversion (R3-proven), buffers right after meta
        size_t avail = (ws_size > metaEnd) ? ws_size - metaEnd : 0;
        int cm = (int)(avail / (2 * tileBytes));
        if (cm > RTILES) cm = RTILES;
        if (cm < 1) cm = 1;
        u16* bufA = (u16*)(ws + metaEnd);
        u16* bufB = (u16*)(ws + metaEnd + (size_t)cm * tileBytes);

        for (int off = 0; off < STILES; off += cm) {
            int nt = (STILES - off < cm) ? (STILES - off) : cm;
            k_gemm_b<0, false, false, true><<<dim3(HID / TN, nt), blk, 0, stream>>>(
                x + (size_t)off * 128 * DIM, sW1, DIM, HID, 0, 0,
                sb1, sg1, sbe1, sm1, sv1, nullptr, nullptr, nullptr, bufA, nullptr);
            k_gemm_b<0, false, false, false><<<dim3(HID / TN, nt), blk, 0, stream>>>(
                bufA, sW2, HID, HID, 0, 0,
                sb2, sg2, sbe2, sm2, sv2, nullptr, nullptr, nullptr, bufB, nullptr);
            k_gemm_b<2, false, false, false><<<dim3(OUTD / TN, nt), blk, 0, stream>>>(
                bufB, sW3, HID, OUTD, 0, 0,
                sb3, nullptr, nullptr, nullptr, nullptr,
                nullptr, nullptr, nullptr, nullptr, out + (size_t)off * 128 * OUTD);
        }
        for (int ro = 0; ro < RTILES; ro += cm) {
            int nt = (RTILES - ro < cm) ? (RTILES - ro) : cm;
            k_gemm_b<0, true, true, true><<<dim3(HID / TN, nt), blk, 0, stream>>>(
                x, W1, DIM, HID, (size_t)HID * DIM, HID,
                b1, g1, be1, m1, v1,
                tile_expert + ro, token_list + (size_t)ro * 128, nullptr, bufA, nullptr);
            k_gemm_b<0, false, true, false><<<dim3(HID / TN, nt), blk, 0, stream>>>(
                bufA, W2, HID, HID, (size_t)HID * HID, HID,
                b2, g2, be2, m2, v2,
                tile_expert + ro, nullptr, nullptr, bufB, nullptr);
            k_gemm_b<1, false, true, false><<<dim3(OUTD / TN, nt), blk, 0, stream>>>(
                bufB, W3, HID, OUTD, (size_t)OUTD * HID, OUTD,
                b3, nullptr, nullptr, nullptr, nullptr,
                tile_expert + ro, token_list + (size_t)ro * 128, row_weight + (size_t)ro * 128,
                nullptr, out);
        }
    }
}